// Round 12
// baseline (68.995 us; speedup 1.0000x reference)
//
#include <hip/hip_runtime.h>
#include <math.h>
#include <stdint.h>

// Problem constants
#define NCH   128      // DIM
#define HH    128
#define WW    128
#define NB    8        // batch
#define NBH   4        // batches per grid-half
#define KS    7
#define MSIZE (128*7*128)        // [u][b][c]

typedef float f32x4 __attribute__((ext_vector_type(4)));

// Explicit async global load/store: volatile asm keeps mutual program order.
#define GLOAD(dst, addr) \
    asm volatile("global_load_dwordx4 %0, %1, off" : "=v"(dst) : "v"(addr))
#define GSTORE(data, addr) \
    asm volatile("global_store_dwordx4 %0, %1, off" :: "v"(addr), "v"(data))

// Separable DFT intermediates: M[u,b,c] = sum_a K[a,b,c] * exp(-2pi i * u*(a-3)/128)
__device__ float g_MAr[MSIZE];
__device__ float g_MAi[MSIZE];
__device__ float g_MBr[MSIZE];
__device__ float g_MBi[MSIZE];

// Kernel 1: build M arrays (A gets 0.9*tanh(A*decay) applied first).
__global__ void kern_factor(const float* __restrict__ A, const float* __restrict__ B) {
    int idx = blockIdx.x * blockDim.x + threadIdx.x;
    if (idx >= MSIZE) return;
    int c  = idx & 127;
    int ub = idx >> 7;
    int b  = ub % 7;
    int u  = ub / 7;

    const float W0 = -6.283185307179586f / 128.0f;
    float mar = 0.f, mai = 0.f, mbr = 0.f, mbi = 0.f;
    float db = (float)(b - 3);
#pragma unroll
    for (int a = 0; a < 7; ++a) {
        float da   = (float)(a - 3);
        float dist = sqrtf(da * da + db * db);
        float dec  = expf(-0.1f * dist);          // exp(-0.3*dist/center), center=3
        float ka   = 0.9f * tanhf(A[c * 49 + a * 7 + b] * dec);
        float kb   = B[c * 49 + a * 7 + b];
        float th   = W0 * (float)(u * (a - 3));
        float s, cc;
        sincosf(th, &s, &cc);                     // exp(i*th) = cc + i*s
        mar = fmaf(ka, cc, mar);
        mai = fmaf(ka, s,  mai);
        mbr = fmaf(kb, cc, mbr);
        mbi = fmaf(kb, s,  mbi);
    }
    g_MAr[idx] = mar;
    g_MAi[idx] = mai;
    g_MBr[idx] = mbr;
    g_MBi[idx] = mbi;
}

// Kernel 2 (fused): finish DFT -> C in registers, apply to 4 batches per block.
// Stream phase = rolling pipeline, store-safe:
//  - loads consumed with decreasing vmcnt(6/4/2/0) (loads retire in order
//    among loads; interleaved stores only make each wait stricter)
//  - every pair has its OWN store-data registers, kept live past the last
//    store via a keep-alive asm -> no WAR on outstanding store data
//    (VMEM stores do NOT snapshot data VGPRs at issue; that was R10/R11's bug)
__global__ void kern_main(const float* __restrict__ x, float* __restrict__ out) {
    __shared__ float s_cs[128];
    __shared__ float s_sn[128];
    int t = threadIdx.x;
    if (t < 128) {
        float th = (6.283185307179586f / 128.0f) * (float)t;
        float s, c;
        sincosf(th, &s, &c);
        s_cs[t] = c;
        s_sn[t] = s;
    }
    __syncthreads();

    int bid  = blockIdx.x;             // 0..4095
    int half = bid >> 11;              // 0 or 1
    int uv   = bid & 2047;             // 0..2047
    int u    = uv >> 4;                // 0..127
    int v    = ((uv & 15) << 3) + (t >> 5);   // 0..127
    int c0   = (t & 31) << 2;          // 0,4,...,124

    float Afr[4] = {0, 0, 0, 0}, Afi[4] = {0, 0, 0, 0};
    float Bfr[4] = {0, 0, 0, 0}, Bfi[4] = {0, 0, 0, 0};

#pragma unroll
    for (int b = 0; b < 7; ++b) {
        int p = (v * (b - 3)) & 127;           // mod 128
        float wr = s_cs[p];
        float wi = -s_sn[p];                   // exp(-2pi i p/128)
        int mbase = (u * 7 + b) * 128 + c0;
        f32x4 mar = *(const f32x4*)(g_MAr + mbase);
        f32x4 mai = *(const f32x4*)(g_MAi + mbase);
        f32x4 mbr = *(const f32x4*)(g_MBr + mbase);
        f32x4 mbi = *(const f32x4*)(g_MBi + mbase);
#pragma unroll
        for (int j = 0; j < 4; ++j) {
            Afr[j] = fmaf(mar[j], wr, fmaf(-mai[j], wi, Afr[j]));
            Afi[j] = fmaf(mar[j], wi, fmaf( mai[j], wr, Afi[j]));
            Bfr[j] = fmaf(mbr[j], wr, fmaf(-mbi[j], wi, Bfr[j]));
            Bfi[j] = fmaf(mbr[j], wi, fmaf( mbi[j], wr, Bfi[j]));
        }
    }

    // S = (1+A)(1+A^2)(1+A^4)(1+A^8); C = S*Bf
    f32x4 cr, ci;
#pragma unroll
    for (int j = 0; j < 4; ++j) {
        float ar = Afr[j], ai = Afi[j];
        float a2r = ar * ar - ai * ai,     a2i = 2.f * ar * ai;
        float a4r = a2r * a2r - a2i * a2i, a4i = 2.f * a2r * a2i;
        float a8r = a4r * a4r - a4i * a4i, a8i = 2.f * a4r * a4i;
        float s1r = 1.f + ar,  s1i = ai;
        float s2r = 1.f + a2r, s2i = a2i;
        float pr  = s1r * s2r - s1i * s2i;
        float pi  = s1r * s2i + s1i * s2r;
        float s3r = 1.f + a4r, s3i = a4i;
        float qr  = pr * s3r - pi * s3i;
        float qi  = pr * s3i + pi * s3r;
        float s4r = 1.f + a8r, s4i = a8i;
        float Sr  = qr * s4r - qi * s4i;
        float Si  = qr * s4i + qi * s4r;
        cr[j] = Sr * Bfr[j] - Si * Bfi[j];
        ci[j] = Sr * Bfi[j] + Si * Bfr[j];
    }

    // Rolling-pipeline stream over 4 batches.
    const size_t BS = (size_t)HH * WW * 2 * NCH;      // batch stride in floats
    size_t base = ((size_t)u * WW + v) * (2 * NCH) + c0 + (size_t)(half * NBH) * BS;

    uint64_t p0 = (uint64_t)(x + base + 0 * BS);
    uint64_t q0 = p0 + NCH * 4;
    uint64_t p1 = (uint64_t)(x + base + 1 * BS);
    uint64_t q1 = p1 + NCH * 4;
    uint64_t p2 = (uint64_t)(x + base + 2 * BS);
    uint64_t q2 = p2 + NCH * 4;
    uint64_t p3 = (uint64_t)(x + base + 3 * BS);
    uint64_t q3 = p3 + NCH * 4;
    uint64_t o0 = (uint64_t)(out + base + 0 * BS);
    uint64_t o1 = (uint64_t)(out + base + 1 * BS);
    uint64_t o2 = (uint64_t)(out + base + 2 * BS);
    uint64_t o3 = (uint64_t)(out + base + 3 * BS);

    f32x4 xr0, xi0, xr1, xi1, xr2, xi2, xr3, xi3;
    GLOAD(xr0, p0);  GLOAD(xi0, q0);
    GLOAD(xr1, p1);  GLOAD(xi1, q1);
    GLOAD(xr2, p2);  GLOAD(xi2, q2);
    GLOAD(xr3, p3);  GLOAD(xi3, q3);

    f32x4 orr0, oii0, orr1, oii1, orr2, oii2, orr3, oii3;

#define PAIR(xr_, xi_, orr_, oii_, od_, WAIT)                          \
    asm volatile(WAIT ::: "memory");                                   \
    __builtin_amdgcn_sched_barrier(0);                                 \
    _Pragma("unroll")                                                  \
    for (int j = 0; j < 4; ++j) {                                      \
        orr_[j] = cr[j] * xr_[j] - ci[j] * xi_[j];                     \
        oii_[j] = cr[j] * xi_[j] + ci[j] * xr_[j];                     \
    }                                                                  \
    GSTORE(orr_, od_);                                                 \
    GSTORE(oii_, (od_) + NCH * 4);

    PAIR(xr0, xi0, orr0, oii0, o0, "s_waitcnt vmcnt(6)")
    PAIR(xr1, xi1, orr1, oii1, o1, "s_waitcnt vmcnt(4)")
    PAIR(xr2, xi2, orr2, oii2, o2, "s_waitcnt vmcnt(2)")
    PAIR(xr3, xi3, orr3, oii3, o3, "s_waitcnt vmcnt(0)")
#undef PAIR

    // Keep every store-data tuple live past all store issues so the register
    // allocator cannot alias them (stores read data VGPRs asynchronously).
    asm volatile("" :: "v"(orr0), "v"(oii0), "v"(orr1), "v"(oii1),
                       "v"(orr2), "v"(oii2), "v"(orr3), "v"(oii3));
}

extern "C" void kernel_launch(void* const* d_in, const int* in_sizes, int n_in,
                              void* d_out, int out_size, void* d_ws, size_t ws_size,
                              hipStream_t stream) {
    const float* x = (const float*)d_in[0];   // (8,128,128,256) f32
    const float* A = (const float*)d_in[1];   // (128,7,7) f32
    const float* B = (const float*)d_in[2];   // (128,7,7) f32
    float* out = (float*)d_out;

    kern_factor<<<(MSIZE + 255) / 256, 256, 0, stream>>>(A, B);
    kern_main<<<4096, 256, 0, stream>>>(x, out);
}

// Round 13
// 55.245 us; speedup vs baseline: 1.2489x; 1.2489x over previous
//
#include <hip/hip_runtime.h>
#include <math.h>

// Problem constants
#define NCH   128      // DIM
#define HH    128
#define WW    128
#define NB    8        // batch
#define NBH   4        // batches per grid-half
#define KS    7
#define MSIZE (128*7*128)        // logical [u][b][c]
#define UCHUNK (7*4*128)         // floats of M per u: [b][arr][c] = 3584

typedef float f32x4 __attribute__((ext_vector_type(4)));

// M relaid per-u contiguous: g_Mall[u][b][arr][c], arr = {Ar,Ai,Br,Bi}
__device__ float g_Mall[128 * UCHUNK];

// Kernel 1: build M arrays (A gets 0.9*tanh(A*decay) applied first).
__global__ void kern_factor(const float* __restrict__ A, const float* __restrict__ B) {
    int idx = blockIdx.x * blockDim.x + threadIdx.x;
    if (idx >= MSIZE) return;
    int c  = idx & 127;
    int ub = idx >> 7;
    int b  = ub % 7;
    int u  = ub / 7;

    const float W0 = -6.283185307179586f / 128.0f;
    float mar = 0.f, mai = 0.f, mbr = 0.f, mbi = 0.f;
    float db = (float)(b - 3);
#pragma unroll
    for (int a = 0; a < 7; ++a) {
        float da   = (float)(a - 3);
        float dist = sqrtf(da * da + db * db);
        float dec  = expf(-0.1f * dist);          // exp(-0.3*dist/center), center=3
        float ka   = 0.9f * tanhf(A[c * 49 + a * 7 + b] * dec);
        float kb   = B[c * 49 + a * 7 + b];
        float th   = W0 * (float)(u * (a - 3));
        float s, cc;
        sincosf(th, &s, &cc);                     // exp(i*th) = cc + i*s
        mar = fmaf(ka, cc, mar);
        mai = fmaf(ka, s,  mai);
        mbr = fmaf(kb, cc, mbr);
        mbi = fmaf(kb, s,  mbi);
    }
    int base = u * UCHUNK + b * 512 + c;          // [u][b][arr][c]
    g_Mall[base +   0] = mar;
    g_Mall[base + 128] = mai;
    g_Mall[base + 256] = mbr;
    g_Mall[base + 384] = mbi;
}

// Kernel 2 (fused): stage this block's M slice (14.3 KB) into LDS once
// (kills the per-thread 28x L2-load burst: 470 MB -> 59 MB of L2 traffic),
// finish DFT -> C in registers, apply to 4 batches (grid 4096 = 2 rounds/CU).
__global__ void kern_main(const float* __restrict__ x, float* __restrict__ out) {
    __shared__ float s_cs[128];
    __shared__ float s_sn[128];
    __shared__ float sM[UCHUNK];                  // [b][arr][c]
    int t = threadIdx.x;
    if (t < 128) {
        float th = (6.283185307179586f / 128.0f) * (float)t;
        float s, c;
        sincosf(th, &s, &c);
        s_cs[t] = c;
        s_sn[t] = s;
    }

    int bid  = blockIdx.x;             // 0..4095
    int half = bid >> 11;              // 0 or 1
    int uv   = bid & 2047;             // 0..2047
    int u    = uv >> 4;                // 0..127
    int v    = ((uv & 15) << 3) + (t >> 5);   // 0..127
    int c0   = (t & 31) << 2;          // 0,4,...,124

    // Cooperative stage of M[u]: 896 f32x4, 256 threads -> 3.5 each, coalesced.
    {
        const float* gm = g_Mall + u * UCHUNK;
        for (int k = t; k < UCHUNK / 4; k += 256) {
            *(f32x4*)&sM[k * 4] = *(const f32x4*)(gm + k * 4);
        }
    }
    __syncthreads();

    float Afr[4] = {0, 0, 0, 0}, Afi[4] = {0, 0, 0, 0};
    float Bfr[4] = {0, 0, 0, 0}, Bfi[4] = {0, 0, 0, 0};

#pragma unroll
    for (int b = 0; b < 7; ++b) {
        int p = (v * (b - 3)) & 127;           // mod 128
        float wr = s_cs[p];
        float wi = -s_sn[p];                   // exp(-2pi i p/128)
        int mbase = b * 512 + c0;
        f32x4 mar = *(const f32x4*)&sM[mbase];
        f32x4 mai = *(const f32x4*)&sM[mbase + 128];
        f32x4 mbr = *(const f32x4*)&sM[mbase + 256];
        f32x4 mbi = *(const f32x4*)&sM[mbase + 384];
#pragma unroll
        for (int j = 0; j < 4; ++j) {
            Afr[j] = fmaf(mar[j], wr, fmaf(-mai[j], wi, Afr[j]));
            Afi[j] = fmaf(mar[j], wi, fmaf( mai[j], wr, Afi[j]));
            Bfr[j] = fmaf(mbr[j], wr, fmaf(-mbi[j], wi, Bfr[j]));
            Bfi[j] = fmaf(mbr[j], wi, fmaf( mbi[j], wr, Bfi[j]));
        }
    }

    // S = (1+A)(1+A^2)(1+A^4)(1+A^8); C = S*Bf
    f32x4 cr, ci;
#pragma unroll
    for (int j = 0; j < 4; ++j) {
        float ar = Afr[j], ai = Afi[j];
        float a2r = ar * ar - ai * ai,     a2i = 2.f * ar * ai;
        float a4r = a2r * a2r - a2i * a2i, a4i = 2.f * a2r * a2i;
        float a8r = a4r * a4r - a4i * a4i, a8i = 2.f * a4r * a4i;
        float s1r = 1.f + ar,  s1i = ai;
        float s2r = 1.f + a2r, s2i = a2i;
        float pr  = s1r * s2r - s1i * s2i;
        float pi  = s1r * s2i + s1i * s2r;
        float s3r = 1.f + a4r, s3i = a4i;
        float qr  = pr * s3r - pi * s3i;
        float qi  = pr * s3i + pi * s3r;
        float s4r = 1.f + a8r, s4i = a8i;
        float Sr  = qr * s4r - qi * s4i;
        float Si  = qr * s4i + qi * s4r;
        cr[j] = Sr * Bfr[j] - Si * Bfi[j];
        ci[j] = Sr * Bfi[j] + Si * Bfr[j];
    }

    // Stream 4 batches (R6 structure: compiler-scheduled loads, NT stores).
    const size_t BS = (size_t)HH * WW * 2 * NCH;      // batch stride in floats
    size_t base = ((size_t)u * WW + v) * (2 * NCH) + c0 + (size_t)(half * NBH) * BS;

    f32x4 xr[NBH], xi[NBH];
#pragma unroll
    for (int bt = 0; bt < NBH; ++bt) {
        xr[bt] = *(const f32x4*)(x + base + (size_t)bt * BS);
        xi[bt] = *(const f32x4*)(x + base + (size_t)bt * BS + NCH);
    }
#pragma unroll
    for (int bt = 0; bt < NBH; ++bt) {
        f32x4 orr, oii;
#pragma unroll
        for (int j = 0; j < 4; ++j) {
            orr[j] = cr[j] * xr[bt][j] - ci[j] * xi[bt][j];
            oii[j] = cr[j] * xi[bt][j] + ci[j] * xr[bt][j];
        }
        __builtin_nontemporal_store(orr, (f32x4*)(out + base + (size_t)bt * BS));
        __builtin_nontemporal_store(oii, (f32x4*)(out + base + (size_t)bt * BS + NCH));
    }
}

extern "C" void kernel_launch(void* const* d_in, const int* in_sizes, int n_in,
                              void* d_out, int out_size, void* d_ws, size_t ws_size,
                              hipStream_t stream) {
    const float* x = (const float*)d_in[0];   // (8,128,128,256) f32
    const float* A = (const float*)d_in[1];   // (128,7,7) f32
    const float* B = (const float*)d_in[2];   // (128,7,7) f32
    float* out = (float*)d_out;

    kern_factor<<<(MSIZE + 255) / 256, 256, 0, stream>>>(A, B);
    kern_main<<<4096, 256, 0, stream>>>(x, out);
}